// Round 2
// baseline (385.332 us; speedup 1.0000x reference)
//
#include <hip/hip_runtime.h>

// MultiHead attention, B=2 S=2048 D=1024 H=16 HD=64, fp32 in/out, bf16 MFMA internally.
// Reference bug reproduced: Q is projected with Wk/bk.

#define Bn 2
#define Sn 2048
#define Dn 1024
#define Hn 16
#define HDn 64

typedef short bs8 __attribute__((ext_vector_type(8)));   // 8 x bf16 (raw bits)
typedef float f32x4 __attribute__((ext_vector_type(4)));

__device__ __forceinline__ short f2bf(float f) {
    union { float f; unsigned u; } x; x.f = f;
    unsigned r = x.u + 0x7fffu + ((x.u >> 16) & 1u);   // RNE
    return (short)(r >> 16);
}

// ---- W [K][N] fp32 -> Wt [N][K] bf16 (tiled transpose) ----
__global__ __launch_bounds__(256) void cvt_w_t(const float* __restrict__ W,
                                               short* __restrict__ Wt) {
    __shared__ float tile[32][33];
    int tx = threadIdx.x & 31;
    int ty = threadIdx.x >> 5;           // 0..7
    int bi = blockIdx.y * 32;            // input row (k) base
    int bo = blockIdx.x * 32;            // input col (n) base
    #pragma unroll
    for (int k2 = 0; k2 < 4; k2++)
        tile[ty + k2*8][tx] = W[(size_t)(bi + ty + k2*8) * Dn + bo + tx];
    __syncthreads();
    #pragma unroll
    for (int k2 = 0; k2 < 4; k2++)
        Wt[(size_t)(bo + ty + k2*8) * Dn + bi + tx] = f2bf(tile[tx][ty + k2*8]);
}

// ---- GEMM: C[M=4096][1024] = A[M][1024] @ Bt[1024][1024]^T + bias ----
// AF32: A is fp32, converted to bf16 during LDS staging (else A is bf16).
// MODE 0: bf16 row-major out. MODE 1: bf16 out transposed to [B][D][S] (for V^T).
// MODE 2: fp32 row-major out (final output).
template<int MODE, bool AF32>
__global__ __launch_bounds__(256) void gemm_bt(const void* __restrict__ Avoid,
                                               const short* __restrict__ Bt,
                                               const float* __restrict__ bias,
                                               void* __restrict__ Cout) {
    constexpr int K = Dn, N = Dn;
    __shared__ __align__(16) short As[128][40];   // +8 pad: 2-way conflicts (free)
    __shared__ __align__(16) short Bs[128][40];
    int tid = threadIdx.x;
    int m0 = blockIdx.x * 128, n0 = blockIdx.y * 128;
    int w = tid >> 6, lane = tid & 63;
    int wr = (w >> 1) * 64, wc = (w & 1) * 64;    // wave -> 64x64 quadrant
    int fr = lane & 15, fq = lane >> 4;
    f32x4 acc[4][4] = {};
    int sr = tid >> 2, sc = (tid & 3) * 8;        // staging: 2 half-tiles of 64 rows

    const float* AgF0 = (const float*)Avoid + (size_t)(m0 + sr) * K + sc;
    const float* AgF1 = (const float*)Avoid + (size_t)(m0 + 64 + sr) * K + sc;
    const short* AgH0 = (const short*)Avoid + (size_t)(m0 + sr) * K + sc;
    const short* AgH1 = (const short*)Avoid + (size_t)(m0 + 64 + sr) * K + sc;
    const short* Bg0  = Bt + (size_t)(n0 + sr) * K + sc;
    const short* Bg1  = Bt + (size_t)(n0 + 64 + sr) * K + sc;

    for (int k0 = 0; k0 < K; k0 += 32) {
        bs8 a0, a1;
        if (AF32) {
            f32x4 lo0 = *reinterpret_cast<const f32x4*>(AgF0 + k0);
            f32x4 hi0 = *reinterpret_cast<const f32x4*>(AgF0 + k0 + 4);
            f32x4 lo1 = *reinterpret_cast<const f32x4*>(AgF1 + k0);
            f32x4 hi1 = *reinterpret_cast<const f32x4*>(AgF1 + k0 + 4);
            #pragma unroll
            for (int e = 0; e < 4; e++) {
                a0[e] = f2bf(lo0[e]); a0[4+e] = f2bf(hi0[e]);
                a1[e] = f2bf(lo1[e]); a1[4+e] = f2bf(hi1[e]);
            }
        } else {
            a0 = *reinterpret_cast<const bs8*>(AgH0 + k0);
            a1 = *reinterpret_cast<const bs8*>(AgH1 + k0);
        }
        bs8 b0 = *reinterpret_cast<const bs8*>(Bg0 + k0);
        bs8 b1 = *reinterpret_cast<const bs8*>(Bg1 + k0);
        __syncthreads();                           // prev compute done before overwrite
        *reinterpret_cast<bs8*>(&As[sr][sc])      = a0;
        *reinterpret_cast<bs8*>(&As[64 + sr][sc]) = a1;
        *reinterpret_cast<bs8*>(&Bs[sr][sc])      = b0;
        *reinterpret_cast<bs8*>(&Bs[64 + sr][sc]) = b1;
        __syncthreads();
        bs8 af[4], bfv[4];
        #pragma unroll
        for (int i = 0; i < 4; i++)
            af[i] = *reinterpret_cast<const bs8*>(&As[wr + i*16 + fr][fq*8]);
        #pragma unroll
        for (int j = 0; j < 4; j++)
            bfv[j] = *reinterpret_cast<const bs8*>(&Bs[wc + j*16 + fr][fq*8]);
        #pragma unroll
        for (int i = 0; i < 4; i++)
            #pragma unroll
            for (int j = 0; j < 4; j++)
                acc[i][j] = __builtin_amdgcn_mfma_f32_16x16x32_bf16(af[i], bfv[j], acc[i][j], 0, 0, 0);
    }

    #pragma unroll
    for (int j = 0; j < 4; j++) {
        int col = n0 + wc + j*16 + fr;
        float bv = bias[col];
        #pragma unroll
        for (int i = 0; i < 4; i++) {
            int row0 = m0 + wr + i*16 + fq*4;
            #pragma unroll
            for (int r = 0; r < 4; r++) {
                float v = acc[i][j][r] + bv;
                if (MODE == 0) {
                    ((short*)Cout)[(size_t)(row0 + r) * N + col] = f2bf(v);
                } else if (MODE == 1) {
                    int t = row0 + r, bb = t >> 11, s = t & (Sn - 1);
                    ((short*)Cout)[(size_t)bb * (Dn*Sn) + (size_t)col * Sn + s] = f2bf(v);
                } else {
                    ((float*)Cout)[(size_t)(row0 + r) * N + col] = v;
                }
            }
        }
    }
}

// ---- Flash attention: Qp/Kp [B*S][D] bf16 (head h = cols h*64..), Vt [B][D][S] bf16 ----
// grid (S/64, B*H); 4 waves; wave w owns q-rows qt*64+w*16 .. +15. Causal.
__global__ __launch_bounds__(256) void attn_fwd(const short* __restrict__ Qp,
                                                const short* __restrict__ Kp,
                                                const short* __restrict__ Vt,
                                                short* __restrict__ O) {
    __shared__ __align__(16) short Ks[64][72];       // [kv][dim], pad 72: bank-uniform
    __shared__ __align__(16) short Vs[64][72];       // [dim(hd)][kv]
    __shared__ __align__(16) short Ps[4][16][72];    // per-wave P tile [qrow][kv]
    int qt = blockIdx.x;
    int bh = blockIdx.y, bb = bh >> 4, h = bh & 15;
    int tid = threadIdx.x, w = tid >> 6, lane = tid & 63;
    int fr = lane & 15, fq = lane >> 4;
    int q0 = qt * 64 + w * 16;

    const short* Qg = Qp + (size_t)(bb * Sn + q0 + fr) * Dn + h * HDn + fq * 8;
    bs8 qf0 = *reinterpret_cast<const bs8*>(Qg);
    bs8 qf1 = *reinterpret_cast<const bs8*>(Qg + 32);

    f32x4 oacc[4] = {};
    float m_run[4], l_run[4];
    #pragma unroll
    for (int r = 0; r < 4; r++) { m_run[r] = -1e30f; l_run[r] = 0.f; }

    int sr = tid >> 2, scE = (tid & 3) * 16;         // staging map
    const short* Kg = Kp + (size_t)(bb * Sn + sr) * Dn + h * HDn + scE;
    const short* Vg = Vt + (size_t)bb * (Dn*Sn) + (size_t)(h * HDn + sr) * Sn + scE;

    for (int kt = 0; kt <= qt; kt++) {
        int kv0 = kt * 64;
        bs8 k0v = *reinterpret_cast<const bs8*>(Kg + (size_t)kv0 * Dn);
        bs8 k1v = *reinterpret_cast<const bs8*>(Kg + (size_t)kv0 * Dn + 8);
        bs8 v0v = *reinterpret_cast<const bs8*>(Vg + kv0);
        bs8 v1v = *reinterpret_cast<const bs8*>(Vg + kv0 + 8);
        __syncthreads();                              // prev PV done before overwrite
        *reinterpret_cast<bs8*>(&Ks[sr][scE])     = k0v;
        *reinterpret_cast<bs8*>(&Ks[sr][scE + 8]) = k1v;
        *reinterpret_cast<bs8*>(&Vs[sr][scE])     = v0v;
        *reinterpret_cast<bs8*>(&Vs[sr][scE + 8]) = v1v;
        __syncthreads();

        // S = Q K^T / 8 (+ causal mask on diagonal tile)
        float p_[4][4];
        bool diag = (kt == qt);
        #pragma unroll
        for (int n = 0; n < 4; n++) {
            bs8 kf0 = *reinterpret_cast<const bs8*>(&Ks[n*16 + fr][fq*8]);
            bs8 kf1 = *reinterpret_cast<const bs8*>(&Ks[n*16 + fr][32 + fq*8]);
            f32x4 s = {};
            s = __builtin_amdgcn_mfma_f32_16x16x32_bf16(qf0, kf0, s, 0, 0, 0);
            s = __builtin_amdgcn_mfma_f32_16x16x32_bf16(qf1, kf1, s, 0, 0, 0);
            #pragma unroll
            for (int r = 0; r < 4; r++) {
                float v = s[r] * 0.125f;
                if (diag) {
                    int kvg = kv0 + n*16 + fr;
                    int qg  = q0 + fq*4 + r;
                    if (kvg > qg) v -= 1e9f;          // matches reference additive mask
                }
                p_[n][r] = v;
            }
        }
        // online softmax, per q-row (row = fq*4+r; reduce over 16-lane col group)
        #pragma unroll
        for (int r = 0; r < 4; r++) {
            float m = fmaxf(fmaxf(p_[0][r], p_[1][r]), fmaxf(p_[2][r], p_[3][r]));
            m = fmaxf(m, __shfl_xor(m, 1));
            m = fmaxf(m, __shfl_xor(m, 2));
            m = fmaxf(m, __shfl_xor(m, 4));
            m = fmaxf(m, __shfl_xor(m, 8));
            float mn  = fmaxf(m_run[r], m);
            float fac = __expf(m_run[r] - mn);
            m_run[r] = mn;
            float ssum = 0.f;
            #pragma unroll
            for (int n = 0; n < 4; n++) {
                float p = __expf(p_[n][r] - mn);
                p_[n][r] = p;
                ssum += p;
            }
            ssum += __shfl_xor(ssum, 1);
            ssum += __shfl_xor(ssum, 2);
            ssum += __shfl_xor(ssum, 4);
            ssum += __shfl_xor(ssum, 8);
            l_run[r] = l_run[r] * fac + ssum;
            oacc[0][r] *= fac; oacc[1][r] *= fac; oacc[2][r] *= fac; oacc[3][r] *= fac;
        }
        // P -> LDS (C-layout -> A-frag layout round trip)
        #pragma unroll
        for (int n = 0; n < 4; n++)
            #pragma unroll
            for (int r = 0; r < 4; r++)
                Ps[w][fq*4 + r][n*16 + fr] = f2bf(p_[n][r]);
        __syncthreads();
        // O += P V   (B-frag reads V^T rows contiguously from Vs)
        #pragma unroll
        for (int kc = 0; kc < 2; kc++) {
            bs8 pf = *reinterpret_cast<const bs8*>(&Ps[w][fr][kc*32 + fq*8]);
            #pragma unroll
            for (int n = 0; n < 4; n++) {
                bs8 vf = *reinterpret_cast<const bs8*>(&Vs[n*16 + fr][kc*32 + fq*8]);
                oacc[n] = __builtin_amdgcn_mfma_f32_16x16x32_bf16(pf, vf, oacc[n], 0, 0, 0);
            }
        }
    }
    float inv[4];
    #pragma unroll
    for (int r = 0; r < 4; r++) inv[r] = 1.f / l_run[r];
    short* Og = O + (size_t)(bb * Sn + q0) * Dn + h * HDn;
    #pragma unroll
    for (int n = 0; n < 4; n++)
        #pragma unroll
        for (int r = 0; r < 4; r++)
            Og[(size_t)(fq*4 + r) * Dn + n*16 + fr] = f2bf(oacc[n][r] * inv[r]);
}

extern "C" void kernel_launch(void* const* d_in, const int* in_sizes, int n_in,
                              void* d_out, int out_size, void* d_ws, size_t ws_size,
                              hipStream_t stream) {
    const float* q  = (const float*)d_in[0];
    const float* k  = (const float*)d_in[1];
    const float* v  = (const float*)d_in[2];
    // d_in[3] = mask (causal; implemented analytically)
    const float* Wk = (const float*)d_in[4];
    const float* bk = (const float*)d_in[5];
    const float* Wv = (const float*)d_in[6];
    const float* bv = (const float*)d_in[7];
    const float* Wo = (const float*)d_in[8];
    const float* bo = (const float*)d_in[9];

    char* ws = (char*)d_ws;
    const size_t MB = (size_t)1 << 20;
    short* Wkt = (short*)(ws + 0*MB);    // 2MB
    short* Wvt = (short*)(ws + 2*MB);    // 2MB
    short* Wot = (short*)(ws + 4*MB);    // 2MB
    short* Qp  = (short*)(ws + 6*MB);    // 8MB
    short* Kp  = (short*)(ws + 14*MB);   // 8MB
    short* Vtp = (short*)(ws + 22*MB);   // 8MB  [B][D][S]
    short* Oa  = (short*)(ws + 30*MB);   // 8MB  attention output (bf16)

    cvt_w_t<<<dim3(32, 32), dim3(256), 0, stream>>>(Wk, Wkt);
    cvt_w_t<<<dim3(32, 32), dim3(256), 0, stream>>>(Wv, Wvt);
    cvt_w_t<<<dim3(32, 32), dim3(256), 0, stream>>>(Wo, Wot);

    dim3 gg(32, 8);  // M=4096 / 128, N=1024 / 128
    gemm_bt<0, true><<<gg, dim3(256), 0, stream>>>(q, Wkt, bk, Qp);   // Q proj (with Wk!)
    gemm_bt<0, true><<<gg, dim3(256), 0, stream>>>(k, Wkt, bk, Kp);   // K proj
    gemm_bt<1, true><<<gg, dim3(256), 0, stream>>>(v, Wvt, bv, Vtp);  // V proj -> V^T layout

    attn_fwd<<<dim3(32, 32), dim3(256), 0, stream>>>(Qp, Kp, Vtp, Oa);

    gemm_bt<2, false><<<gg, dim3(256), 0, stream>>>(Oa, Wot, bo, d_out); // out proj, fp32
}

// Round 3
// 261.058 us; speedup vs baseline: 1.4760x; 1.4760x over previous
//
#include <hip/hip_runtime.h>

// MultiHead attention, B=2 S=2048 D=1024 H=16 HD=64, fp32 in/out, bf16 MFMA internally.
// Reference bug reproduced: Q is projected with Wk/bk.

#define Bn 2
#define Sn 2048
#define Dn 1024
#define Hn 16
#define HDn 64

typedef short bs8 __attribute__((ext_vector_type(8)));   // 8 x bf16 (raw bits)
typedef short s4v __attribute__((ext_vector_type(4)));
typedef float f32x4 __attribute__((ext_vector_type(4)));
typedef unsigned int u32;
typedef unsigned int u32x4 __attribute__((ext_vector_type(4)));

__device__ __forceinline__ short f2bf(float f) {
    u32 x = __builtin_bit_cast(u32, f);
    x = x + 0x7fffu + ((x >> 16) & 1u);   // RNE
    return (short)(x >> 16);
}
__device__ __forceinline__ u32 packbf2(float lo, float hi) {
    u32 a = __builtin_bit_cast(u32, lo);
    u32 b = __builtin_bit_cast(u32, hi);
    a = a + 0x7fffu + ((a >> 16) & 1u);
    b = b + 0x7fffu + ((b >> 16) & 1u);
    return (a >> 16) | (b & 0xffff0000u);
}
__device__ __forceinline__ void gload16(const void* g, void* l) {
    __builtin_amdgcn_global_load_lds(
        (const __attribute__((address_space(1))) u32*)g,
        (__attribute__((address_space(3))) u32*)l, 16, 0, 0);
}

// ---- fp32 q/k/v -> bf16, z-fused over the three tensors ----
__global__ __launch_bounds__(256) void cvt_qkv(const float* __restrict__ q,
                                               const float* __restrict__ k,
                                               const float* __restrict__ v,
                                               short* __restrict__ out) {
    int z = blockIdx.y;
    const float* in = z == 0 ? q : z == 1 ? k : v;
    short* o = out + (size_t)z * (Bn * Sn * Dn);
    int i = blockIdx.x * 256 + threadIdx.x;
    const f32x4* p = reinterpret_cast<const f32x4*>(in) + (size_t)i * 2;
    f32x4 a = p[0], b = p[1];
    bs8 ov;
    ov[0]=f2bf(a[0]); ov[1]=f2bf(a[1]); ov[2]=f2bf(a[2]); ov[3]=f2bf(a[3]);
    ov[4]=f2bf(b[0]); ov[5]=f2bf(b[1]); ov[6]=f2bf(b[2]); ov[7]=f2bf(b[3]);
    reinterpret_cast<bs8*>(o)[i] = ov;
}

// ---- W [K][N] fp32 -> Wt [N][K] bf16 (tiled transpose), z-fused ----
__global__ __launch_bounds__(256) void cvt_w(const float* __restrict__ Wk,
                                             const float* __restrict__ Wv,
                                             const float* __restrict__ Wo,
                                             short* __restrict__ Wt) {
    __shared__ float tile[32][33];
    int z = blockIdx.z;
    const float* W = z == 0 ? Wk : z == 1 ? Wv : Wo;
    short* o = Wt + (size_t)z * Dn * Dn;
    int tx = threadIdx.x & 31;
    int ty = threadIdx.x >> 5;
    int bi = blockIdx.y * 32;
    int bo = blockIdx.x * 32;
    #pragma unroll
    for (int k2 = 0; k2 < 4; k2++)
        tile[ty + k2*8][tx] = W[(size_t)(bi + ty + k2*8) * Dn + bo + tx];
    __syncthreads();
    #pragma unroll
    for (int k2 = 0; k2 < 4; k2++)
        o[(size_t)(bo + ty + k2*8) * Dn + bi + tx] = f2bf(tile[tx][ty + k2*8]);
}

// ---- GEMM: C[4096][1024] = A[4096][1024](bf16) @ Bt[1024][1024]^T + bias ----
// BM=64 BN=128: grid (64,8) = 512 blocks (2/CU). global_load_lds staging (m97).
// MODE 0: bf16 row-major. MODE 1: bf16 -> [B][D][S] (V^T). MODE 2: fp32 row-major.
template<int MODE>
__global__ __launch_bounds__(256) void gemm_bt(const short* __restrict__ A,
                                               const short* __restrict__ Bt,
                                               const float* __restrict__ bias,
                                               void* __restrict__ Cout) {
    constexpr int K = Dn, N = Dn;
    __shared__ __align__(16) short As[64][32];    // linear: required by global_load_lds
    __shared__ __align__(16) short Bs[128][32];
    int tid = threadIdx.x;
    int m0 = blockIdx.x * 64, n0 = blockIdx.y * 128;
    int w = tid >> 6, lane = tid & 63;
    int wr = (w >> 1) * 32, wc = (w & 1) * 64;    // wave -> 32x64 sub-tile
    int fr = lane & 15, fq = lane >> 4;
    f32x4 acc[2][4] = {};
    int srow = tid >> 2, scol = (tid & 3) * 8;
    const short* Ag  = A  + (size_t)(m0 + srow) * K + scol;
    const short* Bg0 = Bt + (size_t)(n0 + srow) * K + scol;
    const short* Bg1 = Bt + (size_t)(n0 + 64 + srow) * K + scol;
    short* AsL  = &As[0][0] + tid * 8;
    short* BsL0 = &Bs[0][0] + tid * 8;
    short* BsL1 = &Bs[0][0] + 2048 + tid * 8;

    for (int k0 = 0; k0 < K; k0 += 32) {
        gload16(Ag + k0, AsL);
        gload16(Bg0 + k0, BsL0);
        gload16(Bg1 + k0, BsL1);
        __syncthreads();                          // drains vmcnt: tiles landed
        bs8 af[2], bfv[4];
        #pragma unroll
        for (int i = 0; i < 2; i++)
            af[i] = *reinterpret_cast<const bs8*>(&As[wr + i*16 + fr][fq*8]);
        #pragma unroll
        for (int j = 0; j < 4; j++)
            bfv[j] = *reinterpret_cast<const bs8*>(&Bs[wc + j*16 + fr][fq*8]);
        #pragma unroll
        for (int i = 0; i < 2; i++)
            #pragma unroll
            for (int j = 0; j < 4; j++)
                acc[i][j] = __builtin_amdgcn_mfma_f32_16x16x32_bf16(af[i], bfv[j], acc[i][j], 0, 0, 0);
        __syncthreads();                          // reads done before next overwrite
    }

    #pragma unroll
    for (int j = 0; j < 4; j++) {
        int col = n0 + wc + j*16 + fr;
        float bv = bias[col];
        #pragma unroll
        for (int i = 0; i < 2; i++) {
            int row0 = m0 + wr + i*16 + fq*4;
            #pragma unroll
            for (int r = 0; r < 4; r++) {
                float vv = acc[i][j][r] + bv;
                if (MODE == 0) {
                    ((short*)Cout)[(size_t)(row0 + r) * N + col] = f2bf(vv);
                } else if (MODE == 1) {
                    int t = row0 + r, bb = t >> 11, s = t & (Sn - 1);
                    ((short*)Cout)[(size_t)bb * (Dn*Sn) + (size_t)col * Sn + s] = f2bf(vv);
                } else {
                    ((float*)Cout)[(size_t)(row0 + r) * N + col] = vv;
                }
            }
        }
    }
}

// ---- Flash attention, swapped-QK^T form ----
// Qp/Kp [B*S][D] bf16 (head h = cols h*64..), Vt [B][D][S] bf16.
// grid (16, B*H): block x does q-tiles {x, 31-x} (uniform 33 kv-tiles).
// 4 waves; wave w owns q-rows qt*64+w*16..+15; lane's q = q0 + (lane&15).
__global__ __launch_bounds__(256) void attn_fwd(const short* __restrict__ Qp,
                                                const short* __restrict__ Kp,
                                                const short* __restrict__ Vt,
                                                short* __restrict__ O) {
    __shared__ __align__(16) char Kb[64 * 128];   // [kv][d], XOR-swizzled rows
    __shared__ __align__(16) char Vb[64 * 128];   // [d][kv], XOR-swizzled rows
    __shared__ __align__(16) short Ot[4][16][72]; // per-wave O^T->O transpose
    int bh = blockIdx.y, bb = bh >> 4, h = bh & 15;
    int tid = threadIdx.x, w = tid >> 6, lane = tid & 63;
    int fr = lane & 15, fq = lane >> 4;
    int hiA = (fq >> 1) & 1;
    int wloc = w * 16 + fr;                       // lane's q, local to the 64-q tile
    const float C1 = 0.18033688011112042f;        // log2(e) / 8

    int sr = tid >> 2;                            // staging row
    int scB = (tid & 3) * 32;                     // staging byte col
    int swz = (sr & 7) << 4;
    int wofs0 = sr * 128 + (scB ^ swz);
    int wofs1 = sr * 128 + ((scB + 16) ^ swz);
    const short* Kg = Kp + (size_t)(bb * Sn + sr) * Dn + h * HDn + (tid & 3) * 16;
    const short* Vg = Vt + (size_t)bb * (Dn * Sn) + (size_t)(h * HDn + sr) * Sn + (tid & 3) * 16;

    for (int hf = 0; hf < 2; hf++) {
        int qt = hf ? (31 - (int)blockIdx.x) : (int)blockIdx.x;
        int q0 = qt * 64 + w * 16;
        const short* Qg = Qp + (size_t)(bb * Sn + q0 + fr) * Dn + h * HDn + fq * 8;
        bs8 qf0 = *reinterpret_cast<const bs8*>(Qg);
        bs8 qf1 = *reinterpret_cast<const bs8*>(Qg + 32);
        f32x4 oacc[4] = {};
        float m_run = -3e38f, l_run = 0.f;

        for (int kt = 0; kt <= qt; kt++) {
            int kv0 = kt * 64;
            bs8 k0v = *reinterpret_cast<const bs8*>(Kg + (size_t)kv0 * Dn);
            bs8 k1v = *reinterpret_cast<const bs8*>(Kg + (size_t)kv0 * Dn + 8);
            bs8 v0v = *reinterpret_cast<const bs8*>(Vg + kv0);
            bs8 v1v = *reinterpret_cast<const bs8*>(Vg + kv0 + 8);
            __syncthreads();                      // prev tile's reads done
            *reinterpret_cast<bs8*>(Kb + wofs0) = k0v;
            *reinterpret_cast<bs8*>(Kb + wofs1) = k1v;
            *reinterpret_cast<bs8*>(Vb + wofs0) = v0v;
            *reinterpret_cast<bs8*>(Vb + wofs1) = v1v;
            __syncthreads();

            // S^T = K Q^T : lane holds S[kv=kv0+16n+4fq+r][q=q0+fr]
            float p[4][4];
            #pragma unroll
            for (int n = 0; n < 4; n++) {
                int row = n * 16 + fr;
                int rs = (row & 7) << 4;
                bs8 kf0 = *reinterpret_cast<const bs8*>(Kb + row * 128 + ((fq * 16) ^ rs));
                bs8 kf1 = *reinterpret_cast<const bs8*>(Kb + row * 128 + ((64 + fq * 16) ^ rs));
                f32x4 t = {};
                t = __builtin_amdgcn_mfma_f32_16x16x32_bf16(kf0, qf0, t, 0, 0, 0);
                t = __builtin_amdgcn_mfma_f32_16x16x32_bf16(kf1, qf1, t, 0, 0, 0);
                #pragma unroll
                for (int r = 0; r < 4; r++) p[n][r] = t[r] * C1;   // log2-units
            }
            if (kt == qt) {                        // causal mask (diag tile only)
                #pragma unroll
                for (int n = 0; n < 4; n++)
                    #pragma unroll
                    for (int r = 0; r < 4; r++)
                        if (n * 16 + fq * 4 + r > wloc) p[n][r] = -2e8f;
            }

            // online softmax: 16 in-register values + 2 cross-fq shuffles
            float mloc = p[0][0];
            #pragma unroll
            for (int n = 0; n < 4; n++)
                #pragma unroll
                for (int r = 0; r < 4; r++) mloc = fmaxf(mloc, p[n][r]);
            mloc = fmaxf(mloc, __shfl_xor(mloc, 16));
            mloc = fmaxf(mloc, __shfl_xor(mloc, 32));
            float mn = fmaxf(m_run, mloc);
            float fac = exp2f(m_run - mn);
            m_run = mn;
            float ssum = 0.f;
            #pragma unroll
            for (int n = 0; n < 4; n++)
                #pragma unroll
                for (int r = 0; r < 4; r++) {
                    float e = exp2f(p[n][r] - mn);
                    p[n][r] = e; ssum += e;
                }
            ssum += __shfl_xor(ssum, 16);
            ssum += __shfl_xor(ssum, 32);
            l_run = l_run * fac + ssum;
            #pragma unroll
            for (int n = 0; n < 4; n++) oacc[n] *= fac;

            // P^T -> PV B-fragment, fully in registers (pack + 12 shfl + selects)
            u32 W0 = packbf2(p[0][0], p[0][1]), W1 = packbf2(p[0][2], p[0][3]);
            u32 W2 = packbf2(p[1][0], p[1][1]), W3 = packbf2(p[1][2], p[1][3]);
            u32 W4 = packbf2(p[2][0], p[2][1]), W5 = packbf2(p[2][2], p[2][3]);
            u32 W6 = packbf2(p[3][0], p[3][1]), W7 = packbf2(p[3][2], p[3][3]);
            u32 sA0 = hiA ? W2 : W0, sA1 = hiA ? W3 : W1;
            u32 sA2 = hiA ? W6 : W4, sA3 = hiA ? W7 : W5;
            u32 sB0 = hiA ? W0 : W2, sB1 = hiA ? W1 : W3;
            u32 sB2 = hiA ? W4 : W6, sB3 = hiA ? W5 : W7;
            u32 x16_0 = (u32)__shfl_xor((int)sA0, 16), x16_1 = (u32)__shfl_xor((int)sA1, 16);
            u32 x16_2 = (u32)__shfl_xor((int)sA2, 16), x16_3 = (u32)__shfl_xor((int)sA3, 16);
            u32 x32_0 = (u32)__shfl_xor((int)sB0, 32), x32_1 = (u32)__shfl_xor((int)sB1, 32);
            u32 x32_2 = (u32)__shfl_xor((int)sB2, 32), x32_3 = (u32)__shfl_xor((int)sB3, 32);
            u32 x48_0 = (u32)__shfl_xor((int)sB0, 48), x48_1 = (u32)__shfl_xor((int)sB1, 48);
            u32 x48_2 = (u32)__shfl_xor((int)sB2, 48), x48_3 = (u32)__shfl_xor((int)sB3, 48);
            u32x4 F0, F1;
            F0[0] = fq==0 ? W0   : fq==1 ? x48_0 : fq==2 ? x32_0 : x16_0;
            F0[1] = fq==0 ? W1   : fq==1 ? x48_1 : fq==2 ? x32_1 : x16_1;
            F0[2] = fq==0 ? x16_0 : fq==1 ? x32_0 : fq==2 ? x48_0 : W2;
            F0[3] = fq==0 ? x16_1 : fq==1 ? x32_1 : fq==2 ? x48_1 : W3;
            F1[0] = fq==0 ? W4   : fq==1 ? x48_2 : fq==2 ? x32_2 : x16_2;
            F1[1] = fq==0 ? W5   : fq==1 ? x48_3 : fq==2 ? x32_3 : x16_3;
            F1[2] = fq==0 ? x16_2 : fq==1 ? x32_2 : fq==2 ? x48_2 : W6;
            F1[3] = fq==0 ? x16_3 : fq==1 ? x32_3 : fq==2 ? x48_3 : W7;
            bs8 pf0 = __builtin_bit_cast(bs8, F0);
            bs8 pf1 = __builtin_bit_cast(bs8, F1);

            // O^T += V^T P^T : oacc[n][r] = O^T[d=16n+4fq+r][q=q0+fr]
            #pragma unroll
            for (int n = 0; n < 4; n++) {
                int row = n * 16 + fr;
                int rs = (row & 7) << 4;
                bs8 vf0 = *reinterpret_cast<const bs8*>(Vb + row * 128 + ((fq * 16) ^ rs));
                bs8 vf1 = *reinterpret_cast<const bs8*>(Vb + row * 128 + ((64 + fq * 16) ^ rs));
                oacc[n] = __builtin_amdgcn_mfma_f32_16x16x32_bf16(vf0, pf0, oacc[n], 0, 0, 0);
                oacc[n] = __builtin_amdgcn_mfma_f32_16x16x32_bf16(vf1, pf1, oacc[n], 0, 0, 0);
            }
        }

        // epilogue: O^T -> O via per-wave LDS tile (wave-private, no barrier)
        float inv = 1.f / l_run;
        #pragma unroll
        for (int n = 0; n < 4; n++) {
            s4v ov;
            #pragma unroll
            for (int r = 0; r < 4; r++) ov[r] = f2bf(oacc[n][r] * inv);
            *reinterpret_cast<s4v*>(&Ot[w][fr][n * 16 + fq * 4]) = ov;
        }
        bs8 o0 = *reinterpret_cast<const bs8*>(&Ot[w][fr][fq * 16]);
        bs8 o1 = *reinterpret_cast<const bs8*>(&Ot[w][fr][fq * 16 + 8]);
        short* Og = O + (size_t)(bb * Sn + q0 + fr) * Dn + h * HDn + fq * 16;
        *reinterpret_cast<bs8*>(Og) = o0;
        *reinterpret_cast<bs8*>(Og + 8) = o1;
    }
}

extern "C" void kernel_launch(void* const* d_in, const int* in_sizes, int n_in,
                              void* d_out, int out_size, void* d_ws, size_t ws_size,
                              hipStream_t stream) {
    const float* q  = (const float*)d_in[0];
    const float* k  = (const float*)d_in[1];
    const float* v  = (const float*)d_in[2];
    // d_in[3] = mask (causal; implemented analytically)
    const float* Wk = (const float*)d_in[4];
    const float* bk = (const float*)d_in[5];
    const float* Wv = (const float*)d_in[6];
    const float* bv = (const float*)d_in[7];
    const float* Wo = (const float*)d_in[8];
    const float* bo = (const float*)d_in[9];

    char* ws = (char*)d_ws;
    const size_t MB = (size_t)1 << 20;
    short* Wall = (short*)ws;                 // 3 x 2MB transposed bf16 weights
    short* Wkt  = Wall;
    short* Wvt  = Wall + (1 << 20);
    short* Wot  = Wall + 2 * (1 << 20);
    short* qb   = (short*)(ws + 6*MB);        // 8MB each
    short* kb   = (short*)(ws + 14*MB);
    short* vb   = (short*)(ws + 22*MB);
    short* Qp   = (short*)(ws + 30*MB);
    short* Kp   = (short*)(ws + 38*MB);
    short* Vtp  = qb;                         // qb dead after Q-proj
    short* Oa   = kb;                         // kb dead after K-proj

    cvt_qkv<<<dim3(2048, 3), dim3(256), 0, stream>>>(q, k, v, qb);
    cvt_w<<<dim3(32, 32, 3), dim3(256), 0, stream>>>(Wk, Wv, Wo, Wall);

    dim3 gg(64, 8);  // BM=64: 512 blocks = 2/CU
    gemm_bt<0><<<gg, dim3(256), 0, stream>>>(qb, Wkt, bk, Qp);   // Q proj (with Wk!)
    gemm_bt<0><<<gg, dim3(256), 0, stream>>>(kb, Wkt, bk, Kp);   // K proj
    gemm_bt<1><<<gg, dim3(256), 0, stream>>>(vb, Wvt, bv, Vtp);  // V proj -> [B][D][S]

    attn_fwd<<<dim3(16, 32), dim3(256), 0, stream>>>(Qp, Kp, Vtp, Oa);

    gemm_bt<2><<<gg, dim3(256), 0, stream>>>(Oa, Wot, bo, d_out); // out proj, fp32
}

// Round 4
// 261.003 us; speedup vs baseline: 1.4764x; 1.0002x over previous
//
#include <hip/hip_runtime.h>

// MultiHead attention, B=2 S=2048 D=1024 H=16 HD=64, fp32 in/out, bf16 MFMA internally.
// Reference bug reproduced: Q is projected with Wk/bk.

#define Bn 2
#define Sn 2048
#define Dn 1024
#define Hn 16
#define HDn 64

typedef short bs8 __attribute__((ext_vector_type(8)));   // 8 x bf16 (raw bits)
typedef float f32x4 __attribute__((ext_vector_type(4)));
typedef unsigned int u32;
typedef unsigned int u32x2 __attribute__((ext_vector_type(2)));

__device__ __forceinline__ short f2bf(float f) {
    u32 x = __builtin_bit_cast(u32, f);
    x = x + 0x7fffu + ((x >> 16) & 1u);   // RNE
    return (short)(x >> 16);
}
// packed f32x2 -> bf16x2 in one VALU op (T12 recipe; RNE, matches f2bf)
__device__ __forceinline__ u32 cvtpk(float lo, float hi) {
    u32 r;
    asm("v_cvt_pk_bf16_f32 %0, %1, %2" : "=v"(r) : "v"(lo), "v"(hi));
    return r;
}
__device__ __forceinline__ void gload16(const void* g, void* l) {
    __builtin_amdgcn_global_load_lds(
        (const __attribute__((address_space(1))) u32*)g,
        (__attribute__((address_space(3))) u32*)l, 16, 0, 0);
}

// ---- fp32 q/k/v -> bf16, z-fused ----
__global__ __launch_bounds__(256) void cvt_qkv(const float* __restrict__ q,
                                               const float* __restrict__ k,
                                               const float* __restrict__ v,
                                               short* __restrict__ out) {
    int z = blockIdx.y;
    const float* in = z == 0 ? q : z == 1 ? k : v;
    short* o = out + (size_t)z * (Bn * Sn * Dn);
    int i = blockIdx.x * 256 + threadIdx.x;
    const f32x4* p = reinterpret_cast<const f32x4*>(in) + (size_t)i * 2;
    f32x4 a = p[0], b = p[1];
    bs8 ov;
    ov[0]=f2bf(a[0]); ov[1]=f2bf(a[1]); ov[2]=f2bf(a[2]); ov[3]=f2bf(a[3]);
    ov[4]=f2bf(b[0]); ov[5]=f2bf(b[1]); ov[6]=f2bf(b[2]); ov[7]=f2bf(b[3]);
    reinterpret_cast<bs8*>(o)[i] = ov;
}

// ---- W [K][N] fp32 -> Wt [N][K] bf16 (tiled transpose), z-fused ----
__global__ __launch_bounds__(256) void cvt_w(const float* __restrict__ Wk,
                                             const float* __restrict__ Wv,
                                             const float* __restrict__ Wo,
                                             short* __restrict__ Wt) {
    __shared__ float tile[32][33];
    int z = blockIdx.z;
    const float* W = z == 0 ? Wk : z == 1 ? Wv : Wo;
    short* o = Wt + (size_t)z * Dn * Dn;
    int tx = threadIdx.x & 31;
    int ty = threadIdx.x >> 5;
    int bi = blockIdx.y * 32;
    int bo = blockIdx.x * 32;
    #pragma unroll
    for (int k2 = 0; k2 < 4; k2++)
        tile[ty + k2*8][tx] = W[(size_t)(bi + ty + k2*8) * Dn + bo + tx];
    __syncthreads();
    #pragma unroll
    for (int k2 = 0; k2 < 4; k2++)
        o[(size_t)(bo + ty + k2*8) * Dn + bi + tx] = f2bf(tile[tx][ty + k2*8]);
}

// ---- Fused projection GEMMs (z-batched): m97 structure, 128x128 tile, BK=32 ----
// z=0: Qp = (q@Wk+bk)*log2(e)/8 ; z=1: Kp = k@Wk+bk ; z=2: Vtp = (v@Wv+bv)^T [B][D][S]
__global__ __launch_bounds__(256) void proj3(const short* __restrict__ qb,
                                             const short* __restrict__ kb,
                                             const short* __restrict__ vb,
                                             const short* __restrict__ Wall,
                                             const float* __restrict__ bk,
                                             const float* __restrict__ bv,
                                             short* __restrict__ Qp,
                                             short* __restrict__ Kp,
                                             short* __restrict__ Vtp) {
    constexpr int K = Dn;
    __shared__ __align__(16) short As[128 * 32];
    __shared__ __align__(16) short Bs[128 * 32];
    int z = blockIdx.z;
    const short* A  = z == 0 ? qb : z == 1 ? kb : vb;
    const short* Bt = z == 2 ? Wall + (1 << 20) : Wall;
    const float* bias = z == 2 ? bv : bk;
    int tid = threadIdx.x;
    int m0 = blockIdx.x * 128, n0 = blockIdx.y * 128;
    int w = tid >> 6, lane = tid & 63;
    int wr = (w >> 1) * 64, wc = (w & 1) * 64;
    int fr = lane & 15, fq = lane >> 4;
    f32x4 acc[4][4] = {};
    const short* Ag  = A  + (size_t)(m0 + (tid >> 2)) * K + (tid & 3) * 8;
    const short* Ag2 = Ag + (size_t)64 * K;
    const short* Bg  = Bt + (size_t)(n0 + (tid >> 2)) * K + (tid & 3) * 8;
    const short* Bg2 = Bg + (size_t)64 * K;
    short* AsL = As + tid * 8;
    short* BsL = Bs + tid * 8;

    for (int k0 = 0; k0 < K; k0 += 32) {
        gload16(Ag + k0, AsL);
        gload16(Ag2 + k0, AsL + 2048);
        gload16(Bg + k0, BsL);
        gload16(Bg2 + k0, BsL + 2048);
        __syncthreads();                      // drains vmcnt: tiles landed
        bs8 af[4], bfv[4];
        #pragma unroll
        for (int i = 0; i < 4; i++)
            af[i] = *reinterpret_cast<const bs8*>(&As[(wr + i*16 + fr) * 32 + fq * 8]);
        #pragma unroll
        for (int j = 0; j < 4; j++)
            bfv[j] = *reinterpret_cast<const bs8*>(&Bs[(wc + j*16 + fr) * 32 + fq * 8]);
        #pragma unroll
        for (int i = 0; i < 4; i++)
            #pragma unroll
            for (int j = 0; j < 4; j++)
                acc[i][j] = __builtin_amdgcn_mfma_f32_16x16x32_bf16(af[i], bfv[j], acc[i][j], 0, 0, 0);
        __syncthreads();
    }

    if (z == 2) {
        #pragma unroll
        for (int j = 0; j < 4; j++) {
            int col = n0 + wc + j*16 + fr;
            float bvv = bias[col];
            #pragma unroll
            for (int i = 0; i < 4; i++) {
                int row0 = m0 + wr + i*16 + fq*4;
                int bb = row0 >> 11, s0 = row0 & (Sn - 1);
                size_t base = (size_t)bb * (Dn * Sn) + (size_t)col * Sn + s0;
                u32x2 pv;
                pv[0] = cvtpk(acc[i][j][0] + bvv, acc[i][j][1] + bvv);
                pv[1] = cvtpk(acc[i][j][2] + bvv, acc[i][j][3] + bvv);
                *reinterpret_cast<u32x2*>(&Vtp[base]) = pv;
            }
        }
    } else {
        float sc = (z == 0) ? 0.18033688011112042f : 1.0f;   // log2(e)/8 folded into Qp
        short* outp = (z == 0) ? Qp : Kp;
        #pragma unroll
        for (int j = 0; j < 4; j++) {
            int col = n0 + wc + j*16 + fr;
            float bvv = bias[col];
            #pragma unroll
            for (int i = 0; i < 4; i++) {
                int row0 = m0 + wr + i*16 + fq*4;
                #pragma unroll
                for (int r = 0; r < 4; r++)
                    outp[(size_t)(row0 + r) * Dn + col] = f2bf((acc[i][j][r] + bvv) * sc);
            }
        }
    }
}

// ---- out-proj GEMM: C[4096][1024] fp32 = A(bf16) @ Bt^T + bias ----
__global__ __launch_bounds__(256) void gemm_out(const short* __restrict__ A,
                                                const short* __restrict__ Bt,
                                                const float* __restrict__ bias,
                                                float* __restrict__ Cout) {
    constexpr int K = Dn, N = Dn;
    __shared__ __align__(16) short As[64][32];
    __shared__ __align__(16) short Bs[128][32];
    int tid = threadIdx.x;
    int m0 = blockIdx.x * 64, n0 = blockIdx.y * 128;
    int w = tid >> 6, lane = tid & 63;
    int wr = (w >> 1) * 32, wc = (w & 1) * 64;
    int fr = lane & 15, fq = lane >> 4;
    f32x4 acc[2][4] = {};
    const short* Ag  = A  + (size_t)(m0 + (tid >> 2)) * K + (tid & 3) * 8;
    const short* Bg0 = Bt + (size_t)(n0 + (tid >> 2)) * K + (tid & 3) * 8;
    const short* Bg1 = Bg0 + (size_t)64 * K;
    short* AsL  = &As[0][0] + tid * 8;
    short* BsL0 = &Bs[0][0] + tid * 8;
    short* BsL1 = BsL0 + 2048;

    for (int k0 = 0; k0 < K; k0 += 32) {
        gload16(Ag + k0, AsL);
        gload16(Bg0 + k0, BsL0);
        gload16(Bg1 + k0, BsL1);
        __syncthreads();
        bs8 af[2], bfv[4];
        #pragma unroll
        for (int i = 0; i < 2; i++)
            af[i] = *reinterpret_cast<const bs8*>(&As[wr + i*16 + fr][fq*8]);
        #pragma unroll
        for (int j = 0; j < 4; j++)
            bfv[j] = *reinterpret_cast<const bs8*>(&Bs[wc + j*16 + fr][fq*8]);
        #pragma unroll
        for (int i = 0; i < 2; i++)
            #pragma unroll
            for (int j = 0; j < 4; j++)
                acc[i][j] = __builtin_amdgcn_mfma_f32_16x16x32_bf16(af[i], bfv[j], acc[i][j], 0, 0, 0);
        __syncthreads();
    }
    #pragma unroll
    for (int j = 0; j < 4; j++) {
        int col = n0 + wc + j*16 + fr;
        float bv = bias[col];
        #pragma unroll
        for (int i = 0; i < 2; i++) {
            int row0 = m0 + wr + i*16 + fq*4;
            #pragma unroll
            for (int r = 0; r < 4; r++)
                Cout[(size_t)(row0 + r) * N + col] = acc[i][j][r] + bv;
        }
    }
}

// ---- Flash attention, swapped-QK^T, LDS P-transpose, defer-max ----
// Qp pre-scaled by log2(e)/8. grid (32, B*H); qt = 31 - bx (heavy first).
__global__ __launch_bounds__(256) void attn_fwd(const short* __restrict__ Qp,
                                                const short* __restrict__ Kp,
                                                const short* __restrict__ Vt,
                                                short* __restrict__ O) {
    __shared__ __align__(16) char Kb[64 * 128];   // [kv][d] bf16, XOR-swizzled rows
    __shared__ __align__(16) char Vb[64 * 128];   // [d][kv] bf16, XOR-swizzled rows
    __shared__ __align__(16) u32  Pw[4][16][36];  // per-wave P^T pair-scatter [q][t]
    __shared__ __align__(16) short Ot[4][16][72]; // per-wave O^T -> O transpose
    int qt = 31 - (int)blockIdx.x;
    int bh = blockIdx.y, bb = bh >> 4, h = bh & 15;
    int tid = threadIdx.x, w = tid >> 6, lane = tid & 63;
    int fr = lane & 15, fq = lane >> 4;
    int wloc = w * 16 + fr;
    int q0 = qt * 64 + w * 16;

    const short* Qg = Qp + (size_t)(bb * Sn + q0 + fr) * Dn + h * HDn + fq * 8;
    bs8 qf0 = *reinterpret_cast<const bs8*>(Qg);
    bs8 qf1 = *reinterpret_cast<const bs8*>(Qg + 32);

    f32x4 oacc[4] = {};
    float m_run = -3e38f, l_run = 0.f;

    int sr = tid >> 2, scB = (tid & 3) * 32, swz = (sr & 7) << 4;
    int wofs0 = sr * 128 + (scB ^ swz);
    int wofs1 = sr * 128 + ((scB + 16) ^ swz);
    const short* Kg = Kp + (size_t)(bb * Sn + sr) * Dn + h * HDn + (tid & 3) * 16;
    const short* Vg = Vt + (size_t)bb * (Dn * Sn) + (size_t)(h * HDn + sr) * Sn + (tid & 3) * 16;

    int rs = (fr & 7) << 4;                       // row&7 == fr&7 for rows n*16+fr
    int rb0 = (fq * 16) ^ rs;
    int rb1 = (64 + fq * 16) ^ rs;
    u32* PwL = &Pw[w][fr][0];
    u32* PwS = PwL + 2 * fq;

    for (int kt = 0; kt <= qt; kt++) {
        int kv0 = kt * 64;
        bs8 k0v = *reinterpret_cast<const bs8*>(Kg + (size_t)kv0 * Dn);
        bs8 k1v = *reinterpret_cast<const bs8*>(Kg + (size_t)kv0 * Dn + 8);
        bs8 v0v = *reinterpret_cast<const bs8*>(Vg + kv0);
        bs8 v1v = *reinterpret_cast<const bs8*>(Vg + kv0 + 8);
        __syncthreads();                          // prev tile's frag reads done
        *reinterpret_cast<bs8*>(Kb + wofs0) = k0v;
        *reinterpret_cast<bs8*>(Kb + wofs1) = k1v;
        *reinterpret_cast<bs8*>(Vb + wofs0) = v0v;
        *reinterpret_cast<bs8*>(Vb + wofs1) = v1v;
        __syncthreads();

        // S^T = K Q^T (already in log2 units): lane holds S[kv0+16n+4fq+r][q0+fr]
        float p[4][4];
        #pragma unroll
        for (int n = 0; n < 4; n++) {
            const char* Krow = Kb + (n * 16 + fr) * 128;
            bs8 kf0 = *reinterpret_cast<const bs8*>(Krow + rb0);
            bs8 kf1 = *reinterpret_cast<const bs8*>(Krow + rb1);
            f32x4 t = {};
            t = __builtin_amdgcn_mfma_f32_16x16x32_bf16(kf0, qf0, t, 0, 0, 0);
            t = __builtin_amdgcn_mfma_f32_16x16x32_bf16(kf1, qf1, t, 0, 0, 0);
            p[n][0] = t[0]; p[n][1] = t[1]; p[n][2] = t[2]; p[n][3] = t[3];
        }
        if (kt == qt) {                           // causal mask (diag tile only)
            #pragma unroll
            for (int n = 0; n < 4; n++)
                #pragma unroll
                for (int r = 0; r < 4; r++)
                    if (n * 16 + fq * 4 + r > wloc) p[n][r] = -1.8e8f;
        }

        // online softmax, defer-max (THR=8 in log2 units)
        float m01 = fmaxf(fmaxf(p[0][0], p[0][1]), fmaxf(p[0][2], p[0][3]));
        float m23 = fmaxf(fmaxf(p[1][0], p[1][1]), fmaxf(p[1][2], p[1][3]));
        float m45 = fmaxf(fmaxf(p[2][0], p[2][1]), fmaxf(p[2][2], p[2][3]));
        float m67 = fmaxf(fmaxf(p[3][0], p[3][1]), fmaxf(p[3][2], p[3][3]));
        float mloc = fmaxf(fmaxf(m01, m23), fmaxf(m45, m67));
        mloc = fmaxf(mloc, __shfl_xor(mloc, 16));
        mloc = fmaxf(mloc, __shfl_xor(mloc, 32));
        if (!__all(mloc <= m_run + 8.0f)) {
            float mn = fmaxf(m_run, mloc);
            float fac = exp2f(m_run - mn);
            m_run = mn;
            l_run *= fac;
            oacc[0] *= fac; oacc[1] *= fac; oacc[2] *= fac; oacc[3] *= fac;
        }
        float ssum = 0.f;
        #pragma unroll
        for (int n = 0; n < 4; n++)
            #pragma unroll
            for (int r = 0; r < 4; r++) {
                float e = exp2f(p[n][r] - m_run);
                p[n][r] = e; ssum += e;
            }
        l_run += ssum;                            // per-lane partial; reduced at end

        // P^T pair-scatter: t = 8n+2fq+h ; read back as B-frag t = [16]+4fq+j'
        #pragma unroll
        for (int n = 0; n < 4; n++) {
            u32x2 pr;
            pr[0] = cvtpk(p[n][0], p[n][1]);
            pr[1] = cvtpk(p[n][2], p[n][3]);
            *reinterpret_cast<u32x2*>(PwS + 8 * n) = pr;
        }
        __builtin_amdgcn_wave_barrier();          // keep LDS scatter before reads
        bs8 pf0 = *reinterpret_cast<const bs8*>(PwL + 4 * fq);
        bs8 pf1 = *reinterpret_cast<const bs8*>(PwL + 16 + 4 * fq);

        // O^T += V^T P^T
        #pragma unroll
        for (int n = 0; n < 4; n++) {
            const char* Vrow = Vb + (n * 16 + fr) * 128;
            bs8 vf0 = *reinterpret_cast<const bs8*>(Vrow + rb0);
            bs8 vf1 = *reinterpret_cast<const bs8*>(Vrow + rb1);
            oacc[n] = __builtin_amdgcn_mfma_f32_16x16x32_bf16(vf0, pf0, oacc[n], 0, 0, 0);
            oacc[n] = __builtin_amdgcn_mfma_f32_16x16x32_bf16(vf1, pf1, oacc[n], 0, 0, 0);
        }
    }

    l_run += __shfl_xor(l_run, 16);
    l_run += __shfl_xor(l_run, 32);
    float inv = 1.f / l_run;
    #pragma unroll
    for (int n = 0; n < 4; n++) {
        u32x2 ov;
        ov[0] = cvtpk(oacc[n][0] * inv, oacc[n][1] * inv);
        ov[1] = cvtpk(oacc[n][2] * inv, oacc[n][3] * inv);
        *reinterpret_cast<u32x2*>(&Ot[w][fr][n * 16 + fq * 4]) = ov;
    }
    __builtin_amdgcn_wave_barrier();
    bs8 o0 = *reinterpret_cast<const bs8*>(&Ot[w][fr][fq * 16]);
    bs8 o1 = *reinterpret_cast<const bs8*>(&Ot[w][fr][fq * 16 + 8]);
    short* Og = O + (size_t)(bb * Sn + q0 + fr) * Dn + h * HDn + fq * 16;
    *reinterpret_cast<bs8*>(Og) = o0;
    *reinterpret_cast<bs8*>(Og + 8) = o1;
}

extern "C" void kernel_launch(void* const* d_in, const int* in_sizes, int n_in,
                              void* d_out, int out_size, void* d_ws, size_t ws_size,
                              hipStream_t stream) {
    const float* q  = (const float*)d_in[0];
    const float* k  = (const float*)d_in[1];
    const float* v  = (const float*)d_in[2];
    // d_in[3] = mask (causal; implemented analytically)
    const float* Wk = (const float*)d_in[4];
    const float* bk = (const float*)d_in[5];
    const float* Wv = (const float*)d_in[6];
    const float* bv = (const float*)d_in[7];
    const float* Wo = (const float*)d_in[8];
    const float* bo = (const float*)d_in[9];

    char* ws = (char*)d_ws;
    const size_t MB = (size_t)1 << 20;
    short* Wall = (short*)ws;                 // Wkt | Wvt | Wot, 2MB each (bf16, [N][K])
    short* Wot  = Wall + 2 * (1 << 20);
    short* qb   = (short*)(ws + 6*MB);        // 8MB each
    short* kb   = (short*)(ws + 14*MB);
    short* vb   = (short*)(ws + 22*MB);
    short* Qp   = (short*)(ws + 30*MB);
    short* Kp   = (short*)(ws + 38*MB);
    short* Vtp  = (short*)(ws + 46*MB);       // [B][D][S]; own buffer (proj3 is fused)
    short* Oa   = qb;                         // qb dead after proj3

    cvt_qkv<<<dim3(2048, 3), dim3(256), 0, stream>>>(q, k, v, qb);
    cvt_w<<<dim3(32, 32, 3), dim3(256), 0, stream>>>(Wk, Wv, Wo, Wall);

    proj3<<<dim3(32, 8, 3), dim3(256), 0, stream>>>(qb, kb, vb, Wall, bk, bv, Qp, Kp, Vtp);

    attn_fwd<<<dim3(32, 32), dim3(256), 0, stream>>>(Qp, Kp, Vtp, Oa);

    gemm_out<<<dim3(64, 8), dim3(256), 0, stream>>>(Oa, Wot, bo, (float*)d_out);
}